// Round 2
// baseline (176.498 us; speedup 1.0000x reference)
//
#include <hip/hip_runtime.h>
#include <hip/hip_bf16.h>
#include <stdint.h>

// Problem constants
#define B_ 8
#define D_ 1024
#define N_ 1024
#define INTER_ 512
#define H_ 16
#define EPS_ 1e-5f

typedef __attribute__((ext_vector_type(8))) short bf16x8;
typedef __attribute__((ext_vector_type(4))) float f32x4;
typedef __attribute__((ext_vector_type(4))) unsigned short u16x4;
typedef __attribute__((ext_vector_type(8))) unsigned short u16x8;

__device__ __forceinline__ unsigned short f2bf(float f) {
  union { float f; uint32_t u; } v; v.f = f;
  uint32_t r = (v.u + 0x7FFFu + ((v.u >> 16) & 1u)) >> 16;  // RNE
  return (unsigned short)r;
}

__device__ __forceinline__ void gload_lds16(const void* g, void* l) {
  __builtin_amdgcn_global_load_lds(
      (const __attribute__((address_space(1))) void*)g,
      (__attribute__((address_space(3))) void*)l, 16, 0, 0);
}

// ---------------- fused prep: transpose-cast v | cast weights | biases+invC
// blocks 0..2047      : transpose v (b,d,n) f32 -> vT (b,n,d) bf16, 64x64 tiles
// blocks 2048..4095   : cast Wt/Wp/Wg -> Wall, Ww -> Wwb
// blocks 4096..4104   : bias concat + invC
__global__ __launch_bounds__(256) void k_prep(
    const float* __restrict__ v, const float* __restrict__ Wt,
    const float* __restrict__ Wp, const float* __restrict__ Wg,
    const float* __restrict__ Ww, const float* __restrict__ bt,
    const float* __restrict__ bp, const float* __restrict__ bg,
    const float* __restrict__ mask, unsigned short* __restrict__ vT,
    unsigned short* __restrict__ Wall, unsigned short* __restrict__ Wwb,
    float* __restrict__ ball, float* __restrict__ invC) {
  const int blk = blockIdx.x, tid = threadIdx.x;
  if (blk < 2048) {
    __shared__ short T[64 * 72];  // [n][d], pitch 72 shorts (144 B, 16B-aligned)
    const int b = blk >> 8, tile = blk & 255;
    const int n0 = (tile & 15) * 64, d0 = (tile >> 4) * 64;
    const float* src = v + ((size_t)b * D_ + d0) * N_ + n0;
    const int c = tid & 15, rg = tid >> 4;
#pragma unroll
    for (int i = 0; i < 4; ++i) {
      const int r = rg * 4 + i;  // d-local
      float4 f = *(const float4*)(src + (size_t)r * N_ + c * 4);
      const int nl = c * 4;
      T[(nl + 0) * 72 + r] = f2bf(f.x);
      T[(nl + 1) * 72 + r] = f2bf(f.y);
      T[(nl + 2) * 72 + r] = f2bf(f.z);
      T[(nl + 3) * 72 + r] = f2bf(f.w);
    }
    __syncthreads();
    unsigned short* dst = vT + ((size_t)b * N_ + n0) * D_ + d0;
    const int ch = tid & 7, nr = tid >> 3;
#pragma unroll
    for (int jj = 0; jj < 2; ++jj) {
      const int nl = nr + jj * 32;
      u16x8 val = *(const u16x8*)&T[nl * 72 + ch * 8];
      *(u16x8*)(dst + (size_t)nl * D_ + ch * 8) = val;
    }
  } else if (blk < 4096) {
    const int idx4 = (blk - 2048) * 256 + tid;
    const int total1 = 1536 * 1024 / 4;
    if (idx4 < total1) {
      const int idx = idx4 * 4;
      const int row = idx >> 10, c = idx & 1023;
      const float* src = row < 512    ? Wt + row * 1024 + c
                         : row < 1024 ? Wp + (row - 512) * 1024 + c
                                      : Wg + (row - 1024) * 1024 + c;
      float4 f = *(const float4*)src;
      u16x4 o = {f2bf(f.x), f2bf(f.y), f2bf(f.z), f2bf(f.w)};
      *(u16x4*)(Wall + idx) = o;
    } else {
      const int idx = (idx4 - total1) * 4;
      float4 f = *(const float4*)(Ww + idx);
      u16x4 o = {f2bf(f.x), f2bf(f.y), f2bf(f.z), f2bf(f.w)};
      *(u16x4*)(Wwb + idx) = o;
    }
  } else if (blk == 4096) {
    for (int i = tid; i < 512; i += 256) {
      ball[i] = bt[i]; ball[512 + i] = bp[i]; ball[1024 + i] = bg[i];
    }
  } else {
    const int b = blk - 4097;
    float s = 0.f;
    for (int i = tid; i < 1024; i += 256) s += mask[b * 1024 + i];
    for (int off = 32; off; off >>= 1) s += __shfl_down(s, off, 64);
    __shared__ float red[4];
    if ((tid & 63) == 0) red[tid >> 6] = s;
    __syncthreads();
    if (tid == 0) invC[b] = 1.0f / (red[0] + red[1] + red[2] + red[3]);
  }
}

// ---------------- GEMM1: [theta;phi;g](o,n) = Wall(o,k) * vT(n,k)^T --------
#define BM 128
#define BN 128
#define BK 64

__global__ __launch_bounds__(256, 2) void k_gemm1(
    const unsigned short* __restrict__ Wall, const unsigned short* __restrict__ vT,
    const float* __restrict__ ball, const float* __restrict__ mask,
    unsigned short* __restrict__ thT, unsigned short* __restrict__ phi,
    unsigned short* __restrict__ g) {
  __shared__ __align__(16) short smem[128 * 132];  // 33792 B: lA+lB / C-stage
  char* lA = (char*)smem;
  char* lB = lA + 16384;
  const int b = blockIdx.z, bx = blockIdx.x, by = blockIdx.y;
  const int tid = threadIdx.x, lane = tid & 63, w = tid >> 6;
  const int wr = w >> 1, wc = w & 1;

  const unsigned short* Abase = Wall + (size_t)(by * BM) * 1024;
  const unsigned short* Bbase = vT + ((size_t)b * N_ + bx * BN) * 1024;

  const int srow = w * 32 + (lane >> 3);
  const int sgl = lane & 7;

  f32x4 acc[4][4] = {};

  for (int kt = 0; kt < 1024 / BK; ++kt) {
#pragma unroll
    for (int i = 0; i < 4; ++i) {
      const int r = srow + i * 8;
      const int gs = sgl ^ (r & 7);
      gload_lds16(Abase + (size_t)r * 1024 + kt * BK + gs * 8,
                  lA + w * 4096 + i * 1024);
      gload_lds16(Bbase + (size_t)r * 1024 + kt * BK + gs * 8,
                  lB + w * 4096 + i * 1024);
    }
    __syncthreads();
#pragma unroll
    for (int kk = 0; kk < 2; ++kk) {
      bf16x8 af[4], bfr[4];
#pragma unroll
      for (int mf = 0; mf < 4; ++mf) {
        const int r = wr * 64 + mf * 16 + (lane & 15);
        int byte = r * 128 + kk * 64 + ((lane >> 4) * 16);
        byte ^= (r & 7) << 4;
        af[mf] = *(const bf16x8*)(lA + byte);
      }
#pragma unroll
      for (int nf = 0; nf < 4; ++nf) {
        const int r = wc * 64 + nf * 16 + (lane & 15);
        int byte = r * 128 + kk * 64 + ((lane >> 4) * 16);
        byte ^= (r & 7) << 4;
        bfr[nf] = *(const bf16x8*)(lB + byte);
      }
#pragma unroll
      for (int mf = 0; mf < 4; ++mf)
#pragma unroll
        for (int nf = 0; nf < 4; ++nf)
          acc[mf][nf] = __builtin_amdgcn_mfma_f32_16x16x32_bf16(
              af[mf], bfr[nf], acc[mf][nf], 0, 0, 0);
    }
    __syncthreads();
  }

  // ---- LDS-staged epilogue: Tc pitch 132 shorts ----
  const int region = by >> 2;
  short* Tc = smem;
  if (region == 0) {
    // stage transposed: Tc[n_l][o_l]
#pragma unroll
    for (int mf = 0; mf < 4; ++mf)
#pragma unroll
      for (int nf = 0; nf < 4; ++nf) {
        const int nl = wc * 64 + nf * 16 + (lane & 15);
        const int ol0 = wr * 64 + mf * 16 + ((lane >> 4) << 2);
        u16x4 o;
#pragma unroll
        for (int r = 0; r < 4; ++r)
          o[r] = f2bf(acc[mf][nf][r] + ball[by * BM + ol0 + r]);
        *(u16x4*)&Tc[nl * 132 + ol0] = o;
      }
  } else {
    // stage direct: Tc[o_l][n_l], mask folded for region 2
#pragma unroll
    for (int mf = 0; mf < 4; ++mf)
#pragma unroll
      for (int nf = 0; nf < 4; ++nf) {
        const int nl = wc * 64 + nf * 16 + (lane & 15);
        const int ol0 = wr * 64 + mf * 16 + ((lane >> 4) << 2);
        const float mv = (region == 2) ? mask[b * 1024 + bx * BN + nl] : 1.0f;
#pragma unroll
        for (int r = 0; r < 4; ++r)
          Tc[(ol0 + r) * 132 + nl] =
              f2bf((acc[mf][nf][r] + ball[by * BM + ol0 + r]) * mv);
      }
  }
  __syncthreads();
  const int ch = tid & 15;
#pragma unroll
  for (int j = 0; j < 8; ++j) {
    const int row = (tid >> 4) + j * 16;
    u16x4 lo = *(const u16x4*)&Tc[row * 132 + ch * 8];
    u16x4 hi = *(const u16x4*)&Tc[row * 132 + ch * 8 + 4];
    u16x8 val = {lo[0], lo[1], lo[2], lo[3], hi[0], hi[1], hi[2], hi[3]};
    unsigned short* dst;
    if (region == 0)
      dst = thT + ((size_t)b * N_ + bx * BN + row) * 512 + by * BM + ch * 8;
    else if (region == 1)
      dst = phi + ((size_t)b * 512 + (by - 4) * BM + row) * 1024 + bx * BN + ch * 8;
    else
      dst = g + ((size_t)b * 512 + (by - 8) * BM + row) * 1024 + bx * BN + ch * 8;
    *(u16x8*)dst = val;
  }
}

// ---------------- S partials: Spart[b,h,s] (32x32 f32) over n in [s*128,..)
__global__ __launch_bounds__(256) void k_Spart(const unsigned short* __restrict__ phi,
                                               const unsigned short* __restrict__ g,
                                               float* __restrict__ Spart) {
  const int s = blockIdx.x, h = blockIdx.y, b = blockIdx.z;
  const int tid = threadIdx.x, lane = tid & 63, w = tid >> 6;
  const unsigned short* pb = phi + ((size_t)b * 512 + h * 32) * 1024 + s * 128;
  const unsigned short* gb = g + ((size_t)b * 512 + h * 32) * 1024 + s * 128;
  const int n = w * 32 + ((lane >> 4) * 8);
  bf16x8 af[2], bfr[2];
#pragma unroll
  for (int mf = 0; mf < 2; ++mf)
    af[mf] = *(const bf16x8*)(pb + (size_t)(mf * 16 + (lane & 15)) * 1024 + n);
#pragma unroll
  for (int nf = 0; nf < 2; ++nf)
    bfr[nf] = *(const bf16x8*)(gb + (size_t)(nf * 16 + (lane & 15)) * 1024 + n);
  f32x4 acc[2][2] = {};
#pragma unroll
  for (int mf = 0; mf < 2; ++mf)
#pragma unroll
    for (int nf = 0; nf < 2; ++nf)
      acc[mf][nf] = __builtin_amdgcn_mfma_f32_16x16x32_bf16(
          af[mf], bfr[nf], acc[mf][nf], 0, 0, 0);
  __shared__ float red[4][32][32];
#pragma unroll
  for (int mf = 0; mf < 2; ++mf)
#pragma unroll
    for (int nf = 0; nf < 2; ++nf)
#pragma unroll
      for (int r = 0; r < 4; ++r)
        red[w][mf * 16 + (lane >> 4) * 4 + r][nf * 16 + (lane & 15)] = acc[mf][nf][r];
  __syncthreads();
  float* dst = Spart + ((size_t)(b * 16 + h) * 8 + s) * 1024;
  const int e0 = tid * 4;
  float4 s0 = *(const float4*)(&red[0][0][0] + e0);
  float4 s1 = *(const float4*)(&red[1][0][0] + e0);
  float4 s2 = *(const float4*)(&red[2][0][0] + e0);
  float4 s3 = *(const float4*)(&red[3][0][0] + e0);
  float4 o = {s0.x + s1.x + s2.x + s3.x, s0.y + s1.y + s2.y + s3.y,
              s0.z + s1.z + s2.z + s3.z, s0.w + s1.w + s2.w + s3.w};
  *(float4*)(dst + e0) = o;
}

// ---------------- M[b](o, h*32+d) = sum_d' Ww[o,h*32+d'] * S[b,h,d,d'] -----
__global__ __launch_bounds__(256) void k_M(const unsigned short* __restrict__ Wwb,
                                           const float* __restrict__ Spart,
                                           unsigned short* __restrict__ M) {
  const int rb = blockIdx.x, h = blockIdx.y, b = blockIdx.z;
  const int tid = threadIdx.x, lane = tid & 63, w = tid >> 6;
  __shared__ short Sb[32 * 40];  // [d][d'], pitch 40 shorts (80 B)
  {
    const int e0 = tid * 4;
    const float* sp = Spart + (size_t)(b * 16 + h) * 8 * 1024 + e0;
    float4 a = {0, 0, 0, 0};
#pragma unroll
    for (int s = 0; s < 8; ++s) {
      float4 p = *(const float4*)(sp + s * 1024);
      a.x += p.x; a.y += p.y; a.z += p.z; a.w += p.w;
    }
    const int row = e0 >> 5, col = e0 & 31;
    u16x4 sv = {f2bf(a.x), f2bf(a.y), f2bf(a.z), f2bf(a.w)};
    *(u16x4*)&Sb[row * 40 + col] = sv;
  }
  __syncthreads();
  const int row0w = rb * 128 + w * 32;
  f32x4 acc[2][2] = {};
  bf16x8 af[2], bfr[2];
#pragma unroll
  for (int mf = 0; mf < 2; ++mf)
    af[mf] = *(const bf16x8*)(Wwb + (size_t)(row0w + mf * 16 + (lane & 15)) * 512 +
                              h * 32 + (lane >> 4) * 8);
#pragma unroll
  for (int nf = 0; nf < 2; ++nf)
    bfr[nf] = *(const bf16x8*)&Sb[(nf * 16 + (lane & 15)) * 40 + (lane >> 4) * 8];
#pragma unroll
  for (int mf = 0; mf < 2; ++mf)
#pragma unroll
    for (int nf = 0; nf < 2; ++nf)
      acc[mf][nf] = __builtin_amdgcn_mfma_f32_16x16x32_bf16(
          af[mf], bfr[nf], acc[mf][nf], 0, 0, 0);
#pragma unroll
  for (int mf = 0; mf < 2; ++mf)
#pragma unroll
    for (int nf = 0; nf < 2; ++nf)
#pragma unroll
      for (int r = 0; r < 4; ++r) {
        const int row = row0w + mf * 16 + (lane >> 4) * 4 + r;
        const int dp = nf * 16 + (lane & 15);
        M[((size_t)b * 1024 + row) * 512 + h * 32 + dp] = f2bf(acc[mf][nf][r]);
      }
}

// ---------------- GEMM2: out = BN(M*thT^T * mask/C + bw)*mask + v ----------
__global__ __launch_bounds__(256, 2) void k_gemm2(
    const unsigned short* __restrict__ M, const unsigned short* __restrict__ thT,
    const float* __restrict__ mask, const float* __restrict__ invC,
    const float* __restrict__ bw, const float* __restrict__ gamma,
    const float* __restrict__ beta, const float* __restrict__ mean,
    const float* __restrict__ var, const float* __restrict__ vin,
    float* __restrict__ out) {
  __shared__ __align__(16) unsigned short lA[BM * BK];
  __shared__ __align__(16) unsigned short lB[BN * BK];
  const int b = blockIdx.z, bx = blockIdx.x, by = blockIdx.y;
  const int tid = threadIdx.x, lane = tid & 63, w = tid >> 6;
  const int wr = w >> 1, wc = w & 1;

  const unsigned short* Abase = M + ((size_t)b * 1024 + by * BM) * 512;
  const unsigned short* Bbase = thT + ((size_t)b * N_ + bx * BN) * 512;

  const int srow = w * 32 + (lane >> 3);
  const int sgl = lane & 7;

  f32x4 acc[4][4] = {};

  for (int kt = 0; kt < 512 / BK; ++kt) {
#pragma unroll
    for (int i = 0; i < 4; ++i) {
      const int r = srow + i * 8;
      const int gs = sgl ^ (r & 7);
      gload_lds16(Abase + (size_t)r * 512 + kt * BK + gs * 8,
                  (char*)lA + w * 4096 + i * 1024);
      gload_lds16(Bbase + (size_t)r * 512 + kt * BK + gs * 8,
                  (char*)lB + w * 4096 + i * 1024);
    }
    __syncthreads();
#pragma unroll
    for (int kk = 0; kk < 2; ++kk) {
      bf16x8 af[4], bfr[4];
#pragma unroll
      for (int mf = 0; mf < 4; ++mf) {
        const int r = wr * 64 + mf * 16 + (lane & 15);
        int byte = r * 128 + kk * 64 + ((lane >> 4) * 16);
        byte ^= (r & 7) << 4;
        af[mf] = *(const bf16x8*)((const char*)lA + byte);
      }
#pragma unroll
      for (int nf = 0; nf < 4; ++nf) {
        const int r = wc * 64 + nf * 16 + (lane & 15);
        int byte = r * 128 + kk * 64 + ((lane >> 4) * 16);
        byte ^= (r & 7) << 4;
        bfr[nf] = *(const bf16x8*)((const char*)lB + byte);
      }
#pragma unroll
      for (int mf = 0; mf < 4; ++mf)
#pragma unroll
        for (int nf = 0; nf < 4; ++nf)
          acc[mf][nf] = __builtin_amdgcn_mfma_f32_16x16x32_bf16(
              af[mf], bfr[nf], acc[mf][nf], 0, 0, 0);
    }
    __syncthreads();
  }

  const float icb = invC[b];
#pragma unroll
  for (int mf = 0; mf < 4; ++mf) {
#pragma unroll
    for (int nf = 0; nf < 4; ++nf) {
      const int col = bx * BN + wc * 64 + nf * 16 + (lane & 15);
      const int row0 = by * BM + wr * 64 + mf * 16 + ((lane >> 4) << 2);
      const float mv = mask[b * 1024 + col];
      const float sc = mv * icb;
#pragma unroll
      for (int r = 0; r < 4; ++r) {
        const int o = row0 + r;
        float val = acc[mf][nf][r] * sc + bw[o];
        const float inv = gamma[o] * rsqrtf(var[o] + EPS_);
        val = (val - mean[o]) * inv + beta[o];
        const size_t idx = ((size_t)b * 1024 + o) * 1024 + col;
        out[idx] = val * mv + vin[idx];
      }
    }
  }
}

extern "C" void kernel_launch(void* const* d_in, const int* in_sizes, int n_in,
                              void* d_out, int out_size, void* d_ws, size_t ws_size,
                              hipStream_t stream) {
  const float* v = (const float*)d_in[0];
  const float* mask = (const float*)d_in[1];
  const float* Wg = (const float*)d_in[2];
  const float* bg = (const float*)d_in[3];
  const float* Wt = (const float*)d_in[4];
  const float* bt = (const float*)d_in[5];
  const float* Wp = (const float*)d_in[6];
  const float* bp = (const float*)d_in[7];
  const float* Ww = (const float*)d_in[8];
  const float* bw = (const float*)d_in[9];
  const float* gamma = (const float*)d_in[10];
  const float* beta = (const float*)d_in[11];
  const float* mean = (const float*)d_in[12];
  const float* var = (const float*)d_in[13];
  float* out = (float*)d_out;

  char* ws = (char*)d_ws;
  unsigned short* vT = (unsigned short*)ws;    ws += 16777216;  // (b,n,d) bf16
  unsigned short* Wall = (unsigned short*)ws;  ws += 3145728;   // (1536,1024)
  unsigned short* Wwb = (unsigned short*)ws;   ws += 1048576;   // (1024,512)
  unsigned short* thT = (unsigned short*)ws;   ws += 8388608;   // (b,n,512)
  unsigned short* phi = (unsigned short*)ws;   ws += 8388608;   // (b,512,n)
  unsigned short* g = (unsigned short*)ws;     ws += 8388608;   // (b,512,n)
  float* Spart = (float*)ws;                   ws += 4194304;   // (b,16,8,32,32) f32
  unsigned short* Mw = (unsigned short*)ws;    ws += 8388608;   // (b,1024,512)
  float* ball = (float*)ws;                    ws += 6144;      // 1536
  float* invC = (float*)ws;                    ws += 32;        // 8

  k_prep<<<4105, 256, 0, stream>>>(v, Wt, Wp, Wg, Ww, bt, bp, bg, mask,
                                   vT, Wall, Wwb, ball, invC);
  k_gemm1<<<dim3(8, 12, 8), 256, 0, stream>>>(Wall, vT, ball, mask, thT, phi, g);
  k_Spart<<<dim3(8, 16, 8), 256, 0, stream>>>(phi, g, Spart);
  k_M<<<dim3(8, 16, 8), 256, 0, stream>>>(Wwb, Spart, Mw);
  k_gemm2<<<dim3(8, 8, 8), 256, 0, stream>>>(Mw, thT, mask, invC, bw, gamma, beta,
                                             mean, var, v, out);
}

// Round 3
// 170.963 us; speedup vs baseline: 1.0324x; 1.0324x over previous
//
#include <hip/hip_runtime.h>
#include <hip/hip_bf16.h>
#include <stdint.h>

// Problem constants
#define B_ 8
#define D_ 1024
#define N_ 1024
#define INTER_ 512
#define H_ 16
#define EPS_ 1e-5f

typedef __attribute__((ext_vector_type(8))) short bf16x8;
typedef __attribute__((ext_vector_type(4))) float f32x4;
typedef __attribute__((ext_vector_type(4))) unsigned short u16x4;
typedef __attribute__((ext_vector_type(8))) unsigned short u16x8;

__device__ __forceinline__ unsigned short f2bf(float f) {
  union { float f; uint32_t u; } v; v.f = f;
  uint32_t r = (v.u + 0x7FFFu + ((v.u >> 16) & 1u)) >> 16;  // RNE
  return (unsigned short)r;
}

__device__ __forceinline__ void gload_lds16(const void* g, void* l) {
  __builtin_amdgcn_global_load_lds(
      (const __attribute__((address_space(1))) void*)g,
      (__attribute__((address_space(3))) void*)l, 16, 0, 0);
}

// ---------------- fused prep: transpose-cast v | cast weights | biases+invC
__global__ __launch_bounds__(256) void k_prep(
    const float* __restrict__ v, const float* __restrict__ Wt,
    const float* __restrict__ Wp, const float* __restrict__ Wg,
    const float* __restrict__ Ww, const float* __restrict__ bt,
    const float* __restrict__ bp, const float* __restrict__ bg,
    const float* __restrict__ mask, unsigned short* __restrict__ vT,
    unsigned short* __restrict__ Wall, unsigned short* __restrict__ Wwb,
    float* __restrict__ ball, float* __restrict__ invC) {
  const int blk = blockIdx.x, tid = threadIdx.x;
  if (blk < 2048) {
    __shared__ short T[64 * 72];
    const int b = blk >> 8, tile = blk & 255;
    const int n0 = (tile & 15) * 64, d0 = (tile >> 4) * 64;
    const float* src = v + ((size_t)b * D_ + d0) * N_ + n0;
    const int c = tid & 15, rg = tid >> 4;
#pragma unroll
    for (int i = 0; i < 4; ++i) {
      const int r = rg * 4 + i;
      float4 f = *(const float4*)(src + (size_t)r * N_ + c * 4);
      const int nl = c * 4;
      T[(nl + 0) * 72 + r] = f2bf(f.x);
      T[(nl + 1) * 72 + r] = f2bf(f.y);
      T[(nl + 2) * 72 + r] = f2bf(f.z);
      T[(nl + 3) * 72 + r] = f2bf(f.w);
    }
    __syncthreads();
    unsigned short* dst = vT + ((size_t)b * N_ + n0) * D_ + d0;
    const int ch = tid & 7, nr = tid >> 3;
#pragma unroll
    for (int jj = 0; jj < 2; ++jj) {
      const int nl = nr + jj * 32;
      u16x8 val = *(const u16x8*)&T[nl * 72 + ch * 8];
      *(u16x8*)(dst + (size_t)nl * D_ + ch * 8) = val;
    }
  } else if (blk < 4096) {
    const int idx4 = (blk - 2048) * 256 + tid;
    const int total1 = 1536 * 1024 / 4;
    if (idx4 < total1) {
      const int idx = idx4 * 4;
      const int row = idx >> 10, c = idx & 1023;
      const float* src = row < 512    ? Wt + row * 1024 + c
                         : row < 1024 ? Wp + (row - 512) * 1024 + c
                                      : Wg + (row - 1024) * 1024 + c;
      float4 f = *(const float4*)src;
      u16x4 o = {f2bf(f.x), f2bf(f.y), f2bf(f.z), f2bf(f.w)};
      *(u16x4*)(Wall + idx) = o;
    } else {
      const int idx = (idx4 - total1) * 4;
      float4 f = *(const float4*)(Ww + idx);
      u16x4 o = {f2bf(f.x), f2bf(f.y), f2bf(f.z), f2bf(f.w)};
      *(u16x4*)(Wwb + idx) = o;
    }
  } else if (blk == 4096) {
    for (int i = tid; i < 512; i += 256) {
      ball[i] = bt[i]; ball[512 + i] = bp[i]; ball[1024 + i] = bg[i];
    }
  } else {
    const int b = blk - 4097;
    float s = 0.f;
    for (int i = tid; i < 1024; i += 256) s += mask[b * 1024 + i];
    for (int off = 32; off; off >>= 1) s += __shfl_down(s, off, 64);
    __shared__ float red[4];
    if ((tid & 63) == 0) red[tid >> 6] = s;
    __syncthreads();
    if (tid == 0) invC[b] = 1.0f / (red[0] + red[1] + red[2] + red[3]);
  }
}

// ---------------- GEMM-A: theta -> thT (by 0..3) | phi+g tiles -> S partials
// by in 0..3  : 128 theta rows, LDS-transposed epilogue -> thT (b,n,i)
// by in 4..11 : rg=by-4; rows = [phi 512+rg*64 .. +64 ; g 1024+rg*64 .. +64]
//               epilogue: bias(+mask on g) -> LDS, S-partial MFMA, Spart f32
#define BM 128
#define BN 128
#define BK 64

__global__ __launch_bounds__(256, 2) void k_gemmA(
    const unsigned short* __restrict__ Wall, const unsigned short* __restrict__ vT,
    const float* __restrict__ ball, const float* __restrict__ mask,
    unsigned short* __restrict__ thT, float* __restrict__ Spart) {
  __shared__ __align__(16) short smem[128 * 132];  // 33792 B
  char* lA = (char*)smem;
  char* lB = lA + 16384;
  const int b = blockIdx.z, bx = blockIdx.x, by = blockIdx.y;
  const int tid = threadIdx.x, lane = tid & 63, w = tid >> 6;
  const int wr = w >> 1, wc = w & 1;
  const bool is_theta = (by < 4);
  const int rg = by - 4;

  // A base per wave: theta -> rows by*128; phig -> waves 0,1 = phi, 2,3 = g
  const unsigned short* Abase;
  if (is_theta)
    Abase = Wall + (size_t)(by * BM) * 1024;
  else
    Abase = (w < 2) ? Wall + (size_t)(512 + rg * 64) * 1024
                    : Wall + (size_t)(1024 + rg * 64 - 64) * 1024;
  const unsigned short* Bbase = vT + ((size_t)b * N_ + bx * BN) * 1024;

  const int srow = w * 32 + (lane >> 3);
  const int sgl = lane & 7;

  f32x4 acc[4][4] = {};

  for (int kt = 0; kt < 1024 / BK; ++kt) {
#pragma unroll
    for (int i = 0; i < 4; ++i) {
      const int r = srow + i * 8;
      const int gs = sgl ^ (r & 7);
      gload_lds16(Abase + (size_t)r * 1024 + kt * BK + gs * 8,
                  lA + w * 4096 + i * 1024);
      gload_lds16(Bbase + (size_t)r * 1024 + kt * BK + gs * 8,
                  lB + w * 4096 + i * 1024);
    }
    __syncthreads();
#pragma unroll
    for (int kk = 0; kk < 2; ++kk) {
      bf16x8 af[4], bfr[4];
#pragma unroll
      for (int mf = 0; mf < 4; ++mf) {
        const int r = wr * 64 + mf * 16 + (lane & 15);
        int byte = r * 128 + kk * 64 + ((lane >> 4) * 16);
        byte ^= (r & 7) << 4;
        af[mf] = *(const bf16x8*)(lA + byte);
      }
#pragma unroll
      for (int nf = 0; nf < 4; ++nf) {
        const int r = wc * 64 + nf * 16 + (lane & 15);
        int byte = r * 128 + kk * 64 + ((lane >> 4) * 16);
        byte ^= (r & 7) << 4;
        bfr[nf] = *(const bf16x8*)(lB + byte);
      }
#pragma unroll
      for (int mf = 0; mf < 4; ++mf)
#pragma unroll
        for (int nf = 0; nf < 4; ++nf)
          acc[mf][nf] = __builtin_amdgcn_mfma_f32_16x16x32_bf16(
              af[mf], bfr[nf], acc[mf][nf], 0, 0, 0);
    }
    __syncthreads();
  }

  short* Tc = smem;  // pitch 132 shorts
  if (is_theta) {
    // stage transposed: Tc[n_l][o_l], bias folded
#pragma unroll
    for (int mf = 0; mf < 4; ++mf)
#pragma unroll
      for (int nf = 0; nf < 4; ++nf) {
        const int nl = wc * 64 + nf * 16 + (lane & 15);
        const int ol0 = wr * 64 + mf * 16 + ((lane >> 4) << 2);
        u16x4 o;
#pragma unroll
        for (int r = 0; r < 4; ++r)
          o[r] = f2bf(acc[mf][nf][r] + ball[by * BM + ol0 + r]);
        *(u16x4*)&Tc[nl * 132 + ol0] = o;
      }
    __syncthreads();
    const int ch = tid & 15;
#pragma unroll
    for (int j = 0; j < 8; ++j) {
      const int row = (tid >> 4) + j * 16;
      u16x4 lo = *(const u16x4*)&Tc[row * 132 + ch * 8];
      u16x4 hi = *(const u16x4*)&Tc[row * 132 + ch * 8 + 4];
      u16x8 val = {lo[0], lo[1], lo[2], lo[3], hi[0], hi[1], hi[2], hi[3]};
      *(u16x8*)(thT + ((size_t)b * N_ + bx * BN + row) * 512 + by * BM + ch * 8) =
          val;
    }
    return;
  }

  // ---- phi/g path: stage tiles to LDS (rows 0-63 phi, 64-127 g) ----
#pragma unroll
  for (int mf = 0; mf < 4; ++mf)
#pragma unroll
    for (int nf = 0; nf < 4; ++nf) {
      const int nl = wc * 64 + nf * 16 + (lane & 15);
      const int ol0 = wr * 64 + mf * 16 + ((lane >> 4) << 2);  // local row
      const float mv = (wr == 1) ? mask[b * 1024 + bx * BN + nl] : 1.0f;
      const int gb = (wr == 0) ? 512 + rg * 64 : 1024 + rg * 64 - 64;  // +local
#pragma unroll
      for (int r = 0; r < 4; ++r)
        Tc[(ol0 + r) * 132 + nl] =
            f2bf((acc[mf][nf][r] + ball[gb + ol0 + r]) * mv);
    }
  __syncthreads();

  // ---- S partials: per head hl (0,1): S[r][c] += phi[hl*32+r][n]*g[hl*32+c][n]
  // wave w handles n-window w*32..+32 (one K=32 MFMA step per frag)
  f32x4 accs[2][2][2] = {};  // [hl][mf][nf]
#pragma unroll
  for (int hl = 0; hl < 2; ++hl) {
    bf16x8 af[2], bfr[2];
#pragma unroll
    for (int mf = 0; mf < 2; ++mf) {
      const int row = hl * 32 + mf * 16 + (lane & 15);
      af[mf] = *(const bf16x8*)&Tc[row * 132 + w * 32 + (lane >> 4) * 8];
    }
#pragma unroll
    for (int nf = 0; nf < 2; ++nf) {
      const int row = 64 + hl * 32 + nf * 16 + (lane & 15);
      bfr[nf] = *(const bf16x8*)&Tc[row * 132 + w * 32 + (lane >> 4) * 8];
    }
#pragma unroll
    for (int mf = 0; mf < 2; ++mf)
#pragma unroll
      for (int nf = 0; nf < 2; ++nf)
        accs[hl][mf][nf] = __builtin_amdgcn_mfma_f32_16x16x32_bf16(
            af[mf], bfr[nf], accs[hl][mf][nf], 0, 0, 0);
  }
  __syncthreads();
  float* red = (float*)smem;  // [2][4][32][32] = 32 KB
#pragma unroll
  for (int hl = 0; hl < 2; ++hl)
#pragma unroll
    for (int mf = 0; mf < 2; ++mf)
#pragma unroll
      for (int nf = 0; nf < 2; ++nf)
#pragma unroll
        for (int r = 0; r < 4; ++r)
          red[((hl * 4 + w) * 32 + mf * 16 + (lane >> 4) * 4 + r) * 32 +
              nf * 16 + (lane & 15)] = accs[hl][mf][nf][r];
  __syncthreads();
  for (int e = tid; e < 2048; e += 256) {
    const int hl = e >> 10, idx = e & 1023;
    const float* rb = red + (hl * 4) * 1024;
    const float sum = rb[idx] + rb[1024 + idx] + rb[2048 + idx] + rb[3072 + idx];
    const int h = rg * 2 + hl;
    Spart[(((size_t)b * 16 + h) * 8 + bx) * 1024 + idx] = sum;
  }
}

// ---------------- M[b](o, h*32+d) = sum_d' Ww[o,h*32+d'] * S[b,h,d,d'] -----
__global__ __launch_bounds__(256) void k_M(const unsigned short* __restrict__ Wwb,
                                           const float* __restrict__ Spart,
                                           unsigned short* __restrict__ M) {
  const int rb = blockIdx.x, h = blockIdx.y, b = blockIdx.z;
  const int tid = threadIdx.x, lane = tid & 63, w = tid >> 6;
  __shared__ short Sb[32 * 40];
  {
    const int e0 = tid * 4;
    const float* sp = Spart + (size_t)(b * 16 + h) * 8 * 1024 + e0;
    float4 a = {0, 0, 0, 0};
#pragma unroll
    for (int s = 0; s < 8; ++s) {
      float4 p = *(const float4*)(sp + s * 1024);
      a.x += p.x; a.y += p.y; a.z += p.z; a.w += p.w;
    }
    const int row = e0 >> 5, col = e0 & 31;
    u16x4 sv = {f2bf(a.x), f2bf(a.y), f2bf(a.z), f2bf(a.w)};
    *(u16x4*)&Sb[row * 40 + col] = sv;
  }
  __syncthreads();
  const int row0w = rb * 128 + w * 32;
  f32x4 acc[2][2] = {};
  bf16x8 af[2], bfr[2];
#pragma unroll
  for (int mf = 0; mf < 2; ++mf)
    af[mf] = *(const bf16x8*)(Wwb + (size_t)(row0w + mf * 16 + (lane & 15)) * 512 +
                              h * 32 + (lane >> 4) * 8);
#pragma unroll
  for (int nf = 0; nf < 2; ++nf)
    bfr[nf] = *(const bf16x8*)&Sb[(nf * 16 + (lane & 15)) * 40 + (lane >> 4) * 8];
#pragma unroll
  for (int mf = 0; mf < 2; ++mf)
#pragma unroll
    for (int nf = 0; nf < 2; ++nf)
      acc[mf][nf] = __builtin_amdgcn_mfma_f32_16x16x32_bf16(
          af[mf], bfr[nf], acc[mf][nf], 0, 0, 0);
#pragma unroll
  for (int mf = 0; mf < 2; ++mf)
#pragma unroll
    for (int nf = 0; nf < 2; ++nf)
#pragma unroll
      for (int r = 0; r < 4; ++r) {
        const int row = row0w + mf * 16 + (lane >> 4) * 4 + r;
        const int dp = nf * 16 + (lane & 15);
        M[((size_t)b * 1024 + row) * 512 + h * 32 + dp] = f2bf(acc[mf][nf][r]);
      }
}

// ---------------- GEMM2: out = BN(M*thT^T * mask/C + bw)*mask + v ----------
__global__ __launch_bounds__(256, 2) void k_gemm2(
    const unsigned short* __restrict__ M, const unsigned short* __restrict__ thT,
    const float* __restrict__ mask, const float* __restrict__ invC,
    const float* __restrict__ bw, const float* __restrict__ gamma,
    const float* __restrict__ beta, const float* __restrict__ mean,
    const float* __restrict__ var, const float* __restrict__ vin,
    float* __restrict__ out) {
  __shared__ __align__(16) unsigned short lA[BM * BK];
  __shared__ __align__(16) unsigned short lB[BN * BK];
  const int b = blockIdx.z, bx = blockIdx.x, by = blockIdx.y;
  const int tid = threadIdx.x, lane = tid & 63, w = tid >> 6;
  const int wr = w >> 1, wc = w & 1;

  const unsigned short* Abase = M + ((size_t)b * 1024 + by * BM) * 512;
  const unsigned short* Bbase = thT + ((size_t)b * N_ + bx * BN) * 512;

  const int srow = w * 32 + (lane >> 3);
  const int sgl = lane & 7;

  f32x4 acc[4][4] = {};

  for (int kt = 0; kt < 512 / BK; ++kt) {
#pragma unroll
    for (int i = 0; i < 4; ++i) {
      const int r = srow + i * 8;
      const int gs = sgl ^ (r & 7);
      gload_lds16(Abase + (size_t)r * 512 + kt * BK + gs * 8,
                  (char*)lA + w * 4096 + i * 1024);
      gload_lds16(Bbase + (size_t)r * 512 + kt * BK + gs * 8,
                  (char*)lB + w * 4096 + i * 1024);
    }
    __syncthreads();
#pragma unroll
    for (int kk = 0; kk < 2; ++kk) {
      bf16x8 af[4], bfr[4];
#pragma unroll
      for (int mf = 0; mf < 4; ++mf) {
        const int r = wr * 64 + mf * 16 + (lane & 15);
        int byte = r * 128 + kk * 64 + ((lane >> 4) * 16);
        byte ^= (r & 7) << 4;
        af[mf] = *(const bf16x8*)((const char*)lA + byte);
      }
#pragma unroll
      for (int nf = 0; nf < 4; ++nf) {
        const int r = wc * 64 + nf * 16 + (lane & 15);
        int byte = r * 128 + kk * 64 + ((lane >> 4) * 16);
        byte ^= (r & 7) << 4;
        bfr[nf] = *(const bf16x8*)((const char*)lB + byte);
      }
#pragma unroll
      for (int mf = 0; mf < 4; ++mf)
#pragma unroll
        for (int nf = 0; nf < 4; ++nf)
          acc[mf][nf] = __builtin_amdgcn_mfma_f32_16x16x32_bf16(
              af[mf], bfr[nf], acc[mf][nf], 0, 0, 0);
    }
    __syncthreads();
  }

  const float icb = invC[b];
#pragma unroll
  for (int mf = 0; mf < 4; ++mf) {
#pragma unroll
    for (int nf = 0; nf < 4; ++nf) {
      const int col = bx * BN + wc * 64 + nf * 16 + (lane & 15);
      const int row0 = by * BM + wr * 64 + mf * 16 + ((lane >> 4) << 2);
      const float mv = mask[b * 1024 + col];
      const float sc = mv * icb;
#pragma unroll
      for (int r = 0; r < 4; ++r) {
        const int o = row0 + r;
        float val = acc[mf][nf][r] * sc + bw[o];
        const float inv = gamma[o] * rsqrtf(var[o] + EPS_);
        val = (val - mean[o]) * inv + beta[o];
        const size_t idx = ((size_t)b * 1024 + o) * 1024 + col;
        out[idx] = val * mv + vin[idx];
      }
    }
  }
}

extern "C" void kernel_launch(void* const* d_in, const int* in_sizes, int n_in,
                              void* d_out, int out_size, void* d_ws, size_t ws_size,
                              hipStream_t stream) {
  const float* v = (const float*)d_in[0];
  const float* mask = (const float*)d_in[1];
  const float* Wg = (const float*)d_in[2];
  const float* bg = (const float*)d_in[3];
  const float* Wt = (const float*)d_in[4];
  const float* bt = (const float*)d_in[5];
  const float* Wp = (const float*)d_in[6];
  const float* bp = (const float*)d_in[7];
  const float* Ww = (const float*)d_in[8];
  const float* bw = (const float*)d_in[9];
  const float* gamma = (const float*)d_in[10];
  const float* beta = (const float*)d_in[11];
  const float* mean = (const float*)d_in[12];
  const float* var = (const float*)d_in[13];
  float* out = (float*)d_out;

  char* ws = (char*)d_ws;
  unsigned short* vT = (unsigned short*)ws;    ws += 16777216;  // (b,n,d) bf16
  unsigned short* Wall = (unsigned short*)ws;  ws += 3145728;   // (1536,1024)
  unsigned short* Wwb = (unsigned short*)ws;   ws += 1048576;   // (1024,512)
  unsigned short* thT = (unsigned short*)ws;   ws += 8388608;   // (b,n,512)
  float* Spart = (float*)ws;                   ws += 4194304;   // (b,16,8,1024) f32
  unsigned short* Mw = (unsigned short*)ws;    ws += 8388608;   // (b,1024,512)
  float* ball = (float*)ws;                    ws += 6144;      // 1536
  float* invC = (float*)ws;                    ws += 32;        // 8

  k_prep<<<4105, 256, 0, stream>>>(v, Wt, Wp, Wg, Ww, bt, bp, bg, mask,
                                   vT, Wall, Wwb, ball, invC);
  k_gemmA<<<dim3(8, 12, 8), 256, 0, stream>>>(Wall, vT, ball, mask, thT, Spart);
  k_M<<<dim3(8, 16, 8), 256, 0, stream>>>(Wwb, Spart, Mw);
  k_gemm2<<<dim3(8, 8, 8), 256, 0, stream>>>(Mw, thT, mask, invC, bw, gamma, beta,
                                             mean, var, v, out);
}